// Round 3
// baseline (370.432 us; speedup 1.0000x reference)
//
#include <hip/hip_runtime.h>

// CTC forward loss, log2-domain DP (matches reference logsumexp semantics,
// immune to the f32 linear-domain dynamic-range truncation that caused R1's
// 64-nat tail error).
// B=256 blocks, 64 threads (1 wave); lane i holds states 2i (blank) and 2i+1
// (label i); lane 63 also holds state 128. One __shfl_up per step is the only
// cross-lane dependency. Emits prefetched in chunks of K=16 t-steps (32
// outstanding gather loads) and converted to log2 off the serial chain.
//
// NOTE: __exp2f/__log2f collide with glibc math.h macros under -x hip (R2
// compile failure) — use amdgcn builtins: __builtin_amdgcn_exp2f = v_exp_f32
// (2^x), __builtin_amdgcn_logf = v_log_f32 (log2(x), despite the name).

constexpr int Bc = 256, Tc = 512, Cc = 512, Lc = 64;
constexpr int BLANK = Cc - 1;
constexpr float EPSF = 1e-7f;
constexpr float NEGI = -1e30f;
constexpr float LN2 = 0.6931471805599453f;
constexpr int K = 16;                         // t-steps per prefetch chunk
constexpr int NC = (Tc - 1 + K - 1) / K;      // 32 chunks covering t=1..511

__device__ __forceinline__ float exp2_hw(float x) { return __builtin_amdgcn_exp2f(x); }
__device__ __forceinline__ float log2_hw(float x) { return __builtin_amdgcn_logf(x); }

__device__ __forceinline__ float lse2(float a, float b) {
    float m = fmaxf(a, b);
    return m + log2_hw(exp2_hw(a - m) + exp2_hw(b - m));
}
__device__ __forceinline__ float lse3(float a, float b, float c) {
    float m = fmaxf(fmaxf(a, b), c);
    return m + log2_hw(exp2_hw(a - m) + exp2_hw(b - m) + exp2_hw(c - m));
}

__global__ __launch_bounds__(64, 1) void ctc_fwd(
    const int* __restrict__ labels,      // [B, L]
    const float* __restrict__ yp,        // [B, T, C] softmax probs
    const int* __restrict__ in_len,      // [B, 1]
    const int* __restrict__ lab_len,     // [B, 1]
    float* __restrict__ out)             // [B, 1]
{
    const int b = blockIdx.x;
    const int lane = threadIdx.x;

    const float* __restrict__ row0 = yp + (size_t)b * (size_t)(Tc * Cc);

    // Reference uses the FULL label array for the DP; lab_len only gates the
    // final extraction.
    const int lab = labels[b * Lc + lane];
    const int labPrev = __shfl_up(lab, 1);
    const bool allow = (lane >= 1 && lab != BLANK && lab != labPrev);

    int til = in_len[b];  if (til > Tc) til = Tc;
    const int lln = lab_len[b];

    // t = 0 init (log2 domain).
    float aB, aL, aH = NEGI;
    {
        float eb0 = log2_hw(row0[BLANK] + EPSF);
        float el0 = log2_hw(row0[lab] + EPSF);
        aB = (lane == 0) ? eb0 : NEGI;
        aL = (lane == 0) ? el0 : NEGI;
    }

    float curL[K], curB[K], nxtL[K], nxtB[K];

    auto loadChunk = [&](int c, float* dL, float* dB) {
        #pragma unroll
        for (int k = 0; k < K; ++k) {
            int t = 1 + c * K + k;
            bool v = (t < Tc);
            size_t o = (size_t)t * Cc;
            dL[k] = v ? row0[o + lab]   : 1.0f;   // per-lane gather (raw p)
            dB[k] = v ? row0[o + BLANK] : 1.0f;   // wave-uniform
        }
    };

    loadChunk(0, curL, curB);

    for (int c = 0; c < NC; ++c) {
        if (c + 1 < NC) loadChunk(c + 1, nxtL, nxtB);   // prefetch next chunk

        #pragma unroll
        for (int k = 0; k < K; ++k) {
            int t = 1 + c * K + k;
            // log2 emit conversion — independent of alpha chain, schedulable
            // early by the compiler across the unrolled body.
            float el = log2_hw(curL[k] + EPSF);
            float eb = log2_hw(curB[k] + EPSF);

            float lp = __shfl_up(aL, 1);                 // alpha[2i-1]
            lp = (lane == 0) ? NEGI : lp;
            float lpm = allow ? lp : NEGI;

            float nB = lse2(aB, lp) + eb;                // s=2i
            float nL = lse3(aL, aB, lpm) + el;           // s=2i+1
            float nH = lse2(aH, aL) + eb;                // s=128 (lane 63)
            if (t < til) { aB = nB; aL = nL; aH = nH; }  // freeze past in_len-1
        }

        #pragma unroll
        for (int k = 0; k < K; ++k) { curL[k] = nxtL[k]; curB[k] = nxtB[k]; }
    }

    // Final states 2*lab_len and 2*lab_len-1 (log2 domain).
    float v1a = __shfl(aB, lln & 63);
    float v1b = __shfl(aH, 63);
    float v1 = (lln >= 64) ? v1b : v1a;
    float v2 = (lln >= 1) ? __shfl(aL, (lln - 1) & 63) : NEGI;

    if (lane == 0) out[b] = -LN2 * lse2(v1, v2);
}

extern "C" void kernel_launch(void* const* d_in, const int* in_sizes, int n_in,
                              void* d_out, int out_size, void* d_ws, size_t ws_size,
                              hipStream_t stream) {
    const int*   y_true       = (const int*)d_in[0];    // [B, L] int32
    const float* y_pred       = (const float*)d_in[1];  // [B, T, C] f32
    const int*   input_length = (const int*)d_in[2];    // [B, 1] int32
    const int*   label_length = (const int*)d_in[3];    // [B, 1] int32
    float*       out          = (float*)d_out;          // [B, 1] f32

    ctc_fwd<<<Bc, 64, 0, stream>>>(y_true, y_pred, input_length, label_length, out);
}